// Round 7
// baseline (2465.412 us; speedup 1.0000x reference)
//
#include <hip/hip_runtime.h>
#include <hip/hip_bf16.h>

typedef __attribute__((ext_vector_type(8))) short   short8;
typedef __attribute__((ext_vector_type(4))) short   shortx4;
typedef __attribute__((ext_vector_type(8))) __bf16  bf16x8;
typedef __attribute__((ext_vector_type(4))) float   floatx4;

__device__ inline float bf2f(short u) {
    return __builtin_bit_cast(float, (unsigned)((unsigned short)u) << 16);
}
__device__ inline short f2bf(float f) {
    return __builtin_bit_cast(short, __float2bfloat16(f));
}

// async 16B global -> LDS (wave-uniform LDS base + lane*16)
__device__ inline void gll16(const void* g, void* l) {
    __builtin_amdgcn_global_load_lds(
        (const __attribute__((address_space(1))) unsigned int*)g,
        (__attribute__((address_space(3))) unsigned int*)l, 16, 0, 0);
}

// ---------------- CSR build ----------------

__global__ void count_kernel(const int* __restrict__ col, int* __restrict__ icnt, int E) {
    int e = blockIdx.x * 256 + threadIdx.x;
    if (e < E) atomicAdd(&icnt[col[e]], 1);
}

__global__ void dinv_cursor_kernel(const int* __restrict__ icnt, float* __restrict__ dinv,
                                   int* __restrict__ cursor, int N) {
    int i = blockIdx.x * 256 + threadIdx.x;
    if (i < N) { dinv[i] = rsqrtf((float)(icnt[i] + 1)); cursor[i] = 0; }
}

// ---- 3-phase multi-block exclusive scan of icnt -> offs (chunk = 1024 elems) ----

__global__ __launch_bounds__(256) void blocksum_kernel(const int* __restrict__ icnt,
                                                       int* __restrict__ bsum, int N) {
    int b = blockIdx.x, t = threadIdx.x;
    int base = b * 1024 + t * 4;
    int s = 0;
    if (base + 3 < N) {
        int4 v = *(const int4*)&icnt[base];
        s = v.x + v.y + v.z + v.w;
    } else {
        for (int i = 0; i < 4; i++) if (base + i < N) s += icnt[base + i];
    }
    __shared__ int red[256];
    red[t] = s;
    __syncthreads();
    for (int o = 128; o > 0; o >>= 1) {
        if (t < o) red[t] += red[t + o];
        __syncthreads();
    }
    if (t == 0) bsum[b] = red[0];
}

__global__ __launch_bounds__(128) void bscan_kernel(int* __restrict__ bsum,
                                                    int* __restrict__ offs, int NB, int N) {
    __shared__ int sh[128];
    int t = threadIdx.x;
    int v = (t < NB) ? bsum[t] : 0;
    sh[t] = v;
    __syncthreads();
    for (int o = 1; o < 128; o <<= 1) {
        int u = (t >= o) ? sh[t - o] : 0;
        __syncthreads();
        sh[t] += u;
        __syncthreads();
    }
    if (t < NB) bsum[t] = sh[t] - v;   // exclusive block offsets
    if (t == 127) offs[N] = sh[127];   // grand total
}

__global__ __launch_bounds__(256) void offs_kernel(const int* __restrict__ icnt,
                                                   const int* __restrict__ bsum,
                                                   int* __restrict__ offs, int N) {
    int b = blockIdx.x, t = threadIdx.x;
    int base = b * 1024 + t * 4;
    int v[4]; int s = 0;
#pragma unroll
    for (int i = 0; i < 4; i++) {
        int idx = base + i;
        v[i] = (idx < N) ? icnt[idx] : 0;
        s += v[i];
    }
    __shared__ int sh[256];
    sh[t] = s;
    __syncthreads();
    for (int o = 1; o < 256; o <<= 1) {
        int u = (t >= o) ? sh[t - o] : 0;
        __syncthreads();
        sh[t] += u;
        __syncthreads();
    }
    int off = bsum[b] + sh[t] - s;
#pragma unroll
    for (int i = 0; i < 4; i++) {
        int idx = base + i;
        if (idx < N) { offs[idx] = off; off += v[i]; }
    }
}

// Single-pass scatter (round-2 proven; binned variant regressed — latency-bound,
// not writeback-BW bound).
__global__ void scatter_kernel(const int* __restrict__ row, const int* __restrict__ col,
                               const int* __restrict__ offs, int* __restrict__ cursor,
                               int* __restrict__ csr, int E) {
    int e = blockIdx.x * 256 + threadIdx.x;
    if (e < E) {
        int c = col[e];
        int p = offs[c] + atomicAdd(&cursor[c], 1);
        csr[p] = row[e];
    }
}

// ---------------- weight prep ----------------

__global__ void w1_tile_kernel(const float* __restrict__ src,
                               __hip_bfloat16* __restrict__ dst) {
    int t = blockIdx.x * 256 + threadIdx.x;
    if (t < 512 * 256) {
        int k = t >> 8, n = t & 255;
        int kc = k >> 5, kl = k & 31;
        int slot = kl >> 3, pos = kl & 7;
        int sl = slot ^ ((n >> 1) & 3);
        dst[kc * 8192 + n * 32 + sl * 8 + pos] = __float2bfloat16(src[t]);
    }
}

__global__ void transpose_cvt_kernel(const float* __restrict__ src,
                                     __hip_bfloat16* __restrict__ dst, int K, int N) {
    int t = blockIdx.x * 256 + threadIdx.x;
    if (t < K * N) { int k = t / N, n = t % N; dst[n * K + k] = __float2bfloat16(src[t]); }
}

// ---------------- fused MLP: h = relu(x@W1+b1)@W2+b2 ----------------
// h is written in FEATURE-PLANE layout [4][N][16] (quarter q = cols 16q..16q+15)
// so the propagation's quarter kernels read/write 3.2 MB L2-resident planes.

__global__ __launch_bounds__(256) void mlp_kernel(
    const float* __restrict__ x, const __hip_bfloat16* __restrict__ W1Tt,
    const float* __restrict__ b1, const __hip_bfloat16* __restrict__ W2T,
    const float* __restrict__ b2, __hip_bfloat16* __restrict__ h, int M)
{
    __shared__ __align__(16) short lds[16384];  // 2 x 16 KB W1 double buffer
    short* Ts = lds;                            // phase-B strip buffer aliases buf0

    const int t = threadIdx.x;
    const int lane = t & 63, wave = t >> 6;
    const int lm = lane & 15, quad = lane >> 4;
    const int block_m = blockIdx.x * 64;
    const short* w2s = (const short*)W2T;
    const char*  w1b = (const char*)W1Tt;

    const int grow = block_m + wave * 16 + lm;
    const bool rok = grow < M;
    const float* xrow = x + (size_t)grow * 512 + quad * 8;
    const floatx4 z4 = (floatx4){0.f, 0.f, 0.f, 0.f};

    const int chunk_base = wave * 4;
    const int gl_off = lane * 16;

    auto stageB = [&](int kc, int buf) {
#pragma unroll
        for (int it = 0; it < 4; it++) {
            int chunk = chunk_base + it;
            gll16(w1b + (size_t)kc * 16384 + chunk * 1024 + gl_off,
                  &lds[buf * 8192 + chunk * 512]);
        }
    };

    floatx4 accA[16];
#pragma unroll
    for (int i = 0; i < 16; i++) accA[i] = z4;

    stageB(0, 0);
    floatx4 a0  = rok ? *(const floatx4*)xrow       : z4;
    floatx4 a1  = rok ? *(const floatx4*)(xrow + 4) : z4;
    floatx4 na0 = z4, na1 = z4;

    const int boff = lm * 32 + ((quad ^ ((lm >> 1) & 3)) << 3);

    __syncthreads();

    for (int kc = 0; kc < 16; kc++) {
        if (kc < 15) {
            stageB(kc + 1, (kc + 1) & 1);
            const float* p = xrow + (kc + 1) * 32;
            na0 = rok ? *(const floatx4*)p       : z4;
            na1 = rok ? *(const floatx4*)(p + 4) : z4;
        }
        short8 afs;
#pragma unroll
        for (int j = 0; j < 4; j++) { afs[j] = f2bf(a0[j]); afs[4 + j] = f2bf(a1[j]); }
        bf16x8 af = __builtin_bit_cast(bf16x8, afs);
        const short* bb = &lds[(kc & 1) * 8192];
#pragma unroll
        for (int nt = 0; nt < 16; nt++) {
            bf16x8 bfr = __builtin_bit_cast(bf16x8, *(const short8*)&bb[nt * 512 + boff]);
            accA[nt] = __builtin_amdgcn_mfma_f32_16x16x32_bf16(af, bfr, accA[nt], 0, 0, 0);
        }
        a0 = na0; a1 = na1;
        __syncthreads();
    }

    floatx4 accB[4];
#pragma unroll
    for (int j = 0; j < 4; j++) accB[j] = z4;

#pragma unroll
    for (int s = 0; s < 4; s++) {
        __syncthreads();
#pragma unroll
        for (int ntl = 0; ntl < 4; ntl++) {
            int nt = s * 4 + ntl;
            float bv = b1[nt * 16 + lm];
#pragma unroll
            for (int r = 0; r < 4; r++) {
                int rowl = wave * 16 + quad * 4 + r;
                Ts[rowl * 72 + ntl * 16 + lm] = f2bf(fmaxf(accA[nt][r] + bv, 0.f));
            }
        }
        __syncthreads();
#pragma unroll
        for (int kk = 0; kk < 2; kk++) {
            bf16x8 af2 = __builtin_bit_cast(bf16x8,
                *(const short8*)&Ts[(wave * 16 + lm) * 72 + kk * 32 + quad * 8]);
#pragma unroll
            for (int nt = 0; nt < 4; nt++) {
                bf16x8 bfr = __builtin_bit_cast(bf16x8,
                    *(const short8*)&w2s[(size_t)(nt * 16 + lm) * 256 + s * 64 + kk * 32 + quad * 8]);
                accB[nt] = __builtin_amdgcn_mfma_f32_16x16x32_bf16(af2, bfr, accB[nt], 0, 0, 0);
            }
        }
    }

    // epilogue -> plane layout: plane = nt, idx = lm
#pragma unroll
    for (int nt = 0; nt < 4; nt++) {
        float bv = b2[nt * 16 + lm];
#pragma unroll
        for (int r = 0; r < 4; r++) {
            int rowg = block_m + wave * 16 + quad * 4 + r;
            if (rowg < M)
                h[((size_t)nt * M + rowg) * 16 + lm] = __float2bfloat16(accB[nt][r] + bv);
        }
    }
}

// ---------------- propagation steps 0..8: quarter-plane, XCD-affine ----------
// z/h live as 4 feature planes [4][N][16] (3.2 MB each). Quarter q is pinned to
// XCD pair {2q,2q+1} via bid%8 (empirical round-robin): each XCD's random
// gathers stay inside ONE plane, which fits its 4 MB L2 -> gathers become
// L2-resident instead of 69% LLC. Wave = 1 node, 2 lanes/edge (32 edges per
// gather instr), xor-tree reduce over the 32 edge groups.

__global__ __launch_bounds__(256) void prop_fast_kernel(
    const short* __restrict__ zq_in, const short* __restrict__ hq,
    const float* __restrict__ dinv, const int* __restrict__ offs,
    const int* __restrict__ csr, short* __restrict__ zq_out, int N)
{
    const int bid = blockIdx.x;
    const int q = (bid >> 1) & 3;                  // quarter = xcd>>1 (xcd = bid&7)
    const int nbk = (bid >> 3) * 2 + (bid & 1);    // node-block within quarter
    const int node = nbk * 4 + (threadIdx.x >> 6);
    if (node >= N) return;                         // wave-uniform
    const int lane = threadIdx.x & 63;
    const int grp = lane >> 1, i2 = lane & 1;
    const short* zp = zq_in + (size_t)q * N * 16;
    const short* hp = hq    + (size_t)q * N * 16;
    float di = dinv[node];
    int s = offs[node], e = offs[node + 1];
    float acc[8] = {0.f, 0.f, 0.f, 0.f, 0.f, 0.f, 0.f, 0.f};

    for (int j0 = s; j0 < e; j0 += 64) {
        int jj = j0 + lane;
        int nbr = 0; float dn = 0.f;
        if (jj < e) { nbr = csr[jj]; dn = dinv[nbr]; }
        bool more = (e - j0) > 32;                 // wave-uniform

        int   nb0 = __shfl(nbr, grp);
        float w0  = __shfl(dn,  grp);
        int   nb1 = __shfl(nbr, 32 + grp);
        float w1  = __shfl(dn,  32 + grp);

        short8 zv0 = *(const short8*)&zp[(size_t)nb0 * 16 + i2 * 8];
        if (more) {
            short8 zv1 = *(const short8*)&zp[(size_t)nb1 * 16 + i2 * 8];
#pragma unroll
            for (int j = 0; j < 8; j++) {
                acc[j] = fmaf(w0, bf2f(zv0[j]), acc[j]);
                acc[j] = fmaf(w1, bf2f(zv1[j]), acc[j]);
            }
        } else {
#pragma unroll
            for (int j = 0; j < 8; j++)
                acc[j] = fmaf(w0, bf2f(zv0[j]), acc[j]);
        }
    }
    // reduce across the 32 edge groups (lane bits 1..5)
#pragma unroll
    for (int j = 0; j < 8; j++) {
        acc[j] += __shfl_xor(acc[j], 2);
        acc[j] += __shfl_xor(acc[j], 4);
        acc[j] += __shfl_xor(acc[j], 8);
        acc[j] += __shfl_xor(acc[j], 16);
        acc[j] += __shfl_xor(acc[j], 32);
    }

    short8 zv = *(const short8*)&zp[(size_t)node * 16 + i2 * 8];
    short8 hv = *(const short8*)&hp[(size_t)node * 16 + i2 * 8];
    if (lane < 2) {
        short8 o8;
#pragma unroll
        for (int j = 0; j < 8; j++) {
            float v = 0.9f * (di * acc[j] + di * di * bf2f(zv[j])) + 0.1f * bf2f(hv[j]);
            o8[j] = f2bf(v);
        }
        *(short8*)&zq_out[((size_t)q * N + node) * 16 + i2 * 8] = o8;
    }
}

// ---------------- propagation last step: full row + log_softmax --------------
// 8 groups x 8-feature chunks (round-2/6 proven structure), gathers re-addressed
// into the plane layout: lane i covers features i*8..i*8+8 = plane i>>1, half i&1.

__global__ __launch_bounds__(256) void prop_last_kernel(
    const short* __restrict__ zq_in, const short* __restrict__ hq,
    const float* __restrict__ dinv, const int* __restrict__ offs,
    const int* __restrict__ csr, float* __restrict__ out, int N)
{
    int node = blockIdx.x * 4 + (threadIdx.x >> 6);
    if (node >= N) return;  // wave-uniform
    int lane = threadIdx.x & 63;
    int g = lane >> 3, i = lane & 7;
    const int pl = i >> 1, ph = i & 1;
    const short* zp = zq_in + (size_t)pl * N * 16;
    const short* hp = hq    + (size_t)pl * N * 16;
    float di = dinv[node];
    int s = offs[node], e = offs[node + 1];
    float acc[8] = {0.f, 0.f, 0.f, 0.f, 0.f, 0.f, 0.f, 0.f};

    for (int j0 = s; j0 < e; j0 += 64) {
        int jj = j0 + lane;
        int nbr = 0; float dn = 0.f;
        if (jj < e) { nbr = csr[jj]; dn = dinv[nbr]; }
        bool more = (e - j0) > 32;  // wave-uniform

        int nb[8]; float wv[8];
#pragma unroll
        for (int tt = 0; tt < 8; tt++) {
            int src = tt * 8 + g;
            nb[tt] = __shfl(nbr, src);
            wv[tt] = __shfl(dn, src);
        }
        short8 zv[8];
#pragma unroll
        for (int tt = 0; tt < 4; tt++)
            zv[tt] = *(const short8*)&zp[(size_t)nb[tt] * 16 + ph * 8];
        if (more) {
#pragma unroll
            for (int tt = 4; tt < 8; tt++)
                zv[tt] = *(const short8*)&zp[(size_t)nb[tt] * 16 + ph * 8];
        }
#pragma unroll
        for (int tt = 0; tt < 4; tt++)
#pragma unroll
            for (int j = 0; j < 8; j++)
                acc[j] = fmaf(wv[tt], bf2f(zv[tt][j]), acc[j]);
        if (more) {
#pragma unroll
            for (int tt = 4; tt < 8; tt++)
#pragma unroll
                for (int j = 0; j < 8; j++)
                    acc[j] = fmaf(wv[tt], bf2f(zv[tt][j]), acc[j]);
        }
    }
#pragma unroll
    for (int j = 0; j < 8; j++) {
        acc[j] += __shfl_xor(acc[j], 8);
        acc[j] += __shfl_xor(acc[j], 16);
        acc[j] += __shfl_xor(acc[j], 32);
    }

    short8 zv = *(const short8*)&zp[(size_t)node * 16 + ph * 8];
    short8 hv = *(const short8*)&hp[(size_t)node * 16 + ph * 8];
    float v[8];
#pragma unroll
    for (int j = 0; j < 8; j++)
        v[j] = 0.9f * (di * acc[j] + di * di * bf2f(zv[j])) + 0.1f * bf2f(hv[j]);

    float m = v[0];
#pragma unroll
    for (int j = 1; j < 8; j++) m = fmaxf(m, v[j]);
    m = fmaxf(m, __shfl_xor(m, 1));
    m = fmaxf(m, __shfl_xor(m, 2));
    m = fmaxf(m, __shfl_xor(m, 4));
    float ss = 0.f;
#pragma unroll
    for (int j = 0; j < 8; j++) ss += expf(v[j] - m);
    ss += __shfl_xor(ss, 1);
    ss += __shfl_xor(ss, 2);
    ss += __shfl_xor(ss, 4);
    float ls = m + logf(ss);
    if (g == 0) {
        floatx4 o0, o1;
#pragma unroll
        for (int j = 0; j < 4; j++) { o0[j] = v[j] - ls; o1[j] = v[4 + j] - ls; }
        *(floatx4*)&out[(size_t)node * 64 + i * 8]     = o0;
        *(floatx4*)&out[(size_t)node * 64 + i * 8 + 4] = o1;
    }
}

// ---------------- launch ----------------

extern "C" void kernel_launch(void* const* d_in, const int* in_sizes, int n_in,
                              void* d_out, int out_size, void* d_ws, size_t ws_size,
                              hipStream_t stream) {
    const float* x  = (const float*)d_in[0];
    const int*   ei = (const int*)d_in[1];
    const float* W1 = (const float*)d_in[2];
    const float* b1 = (const float*)d_in[3];
    const float* W2 = (const float*)d_in[4];
    const float* b2 = (const float*)d_in[5];
    float* out = (float*)d_out;

    const int FIN = 512, FH = 256, FO = 64;
    const int N = in_sizes[0] / FIN;
    const int E = in_sizes[1] / 2;
    const int* erow = ei;
    const int* ecol = ei + E;

    char* w = (char*)d_ws;
    size_t o = 0;
    auto take = [&](size_t bytes) -> void* {
        void* p = w + o;
        o += (bytes + 511) & ~(size_t)511;
        return p;
    };
    int*   icnt   = (int*)  take((size_t)N * 4);
    float* dinv   = (float*)take((size_t)N * 4);
    int*   offs   = (int*)  take((size_t)(N + 1) * 4);
    int*   cursor = (int*)  take((size_t)N * 4);
    int*   csr    = (int*)  take((size_t)E * 4);
    int*   bsum   = (int*)  take((size_t)128 * 4);
    __hip_bfloat16* W1Tt = (__hip_bfloat16*)take((size_t)FIN * FH * 2);
    __hip_bfloat16* W2T  = (__hip_bfloat16*)take((size_t)FH * FO * 2);
    short* hbuf = (short*)take((size_t)N * FO * 2);  // plane layout [4][N][16]
    short* zA   = (short*)take((size_t)N * FO * 2);  // plane layout
    short* zB   = (short*)out;  // alias: bf16 z planes (12.8 MB) in f32 out (25.6 MB)

    const int NB = (N + 1023) / 1024;  // scan blocks (<=128 for bscan)

    (void)hipMemsetAsync(icnt, 0, (size_t)N * 4, stream);
    count_kernel<<<(E + 255) / 256, 256, 0, stream>>>(ecol, icnt, E);
    dinv_cursor_kernel<<<(N + 255) / 256, 256, 0, stream>>>(icnt, dinv, cursor, N);
    blocksum_kernel<<<NB, 256, 0, stream>>>(icnt, bsum, N);
    bscan_kernel<<<1, 128, 0, stream>>>(bsum, offs, NB, N);
    offs_kernel<<<NB, 256, 0, stream>>>(icnt, bsum, offs, N);
    scatter_kernel<<<(E + 255) / 256, 256, 0, stream>>>(erow, ecol, offs, cursor, csr, E);
    w1_tile_kernel<<<(FIN * FH + 255) / 256, 256, 0, stream>>>(W1, W1Tt);
    transpose_cvt_kernel<<<(FH * FO + 255) / 256, 256, 0, stream>>>(W2, W2T, FH, FO);

    mlp_kernel<<<(N + 63) / 64, 256, 0, stream>>>(x, W1Tt, b1, W2T, b2,
                                                  (__hip_bfloat16*)hbuf, N);

    const int grid_fast = 8 * ((N + 7) / 8);  // 8-aligned for the XCD swizzle
    const short* zin = hbuf;
    for (int k = 0; k < 9; k++) {
        short* zout = (k & 1) ? zB : zA;
        prop_fast_kernel<<<grid_fast, 256, 0, stream>>>(zin, hbuf, dinv, offs, csr,
                                                        zout, N);
        zin = zout;
    }
    // k=8 wrote zA; last step reads zA and overwrites out
    prop_last_kernel<<<(N + 3) / 4, 256, 0, stream>>>(zin, hbuf, dinv, offs, csr,
                                                      out, N);
}

// Round 8
// 1212.548 us; speedup vs baseline: 2.0332x; 2.0332x over previous
//
#include <hip/hip_runtime.h>
#include <hip/hip_bf16.h>

typedef __attribute__((ext_vector_type(8))) short   short8;
typedef __attribute__((ext_vector_type(4))) short   shortx4;
typedef __attribute__((ext_vector_type(8))) __bf16  bf16x8;
typedef __attribute__((ext_vector_type(4))) float   floatx4;

__device__ inline float bf2f(short u) {
    return __builtin_bit_cast(float, (unsigned)((unsigned short)u) << 16);
}
__device__ inline short f2bf(float f) {
    return __builtin_bit_cast(short, __float2bfloat16(f));
}

// async 16B global -> LDS (wave-uniform LDS base + lane*16)
__device__ inline void gll16(const void* g, void* l) {
    __builtin_amdgcn_global_load_lds(
        (const __attribute__((address_space(1))) unsigned int*)g,
        (__attribute__((address_space(3))) unsigned int*)l, 16, 0, 0);
}

// ---------------- CSR build ----------------

__global__ void count_kernel(const int* __restrict__ col, int* __restrict__ icnt, int E) {
    int e = blockIdx.x * 256 + threadIdx.x;
    if (e < E) atomicAdd(&icnt[col[e]], 1);
}

__global__ void dinv_cursor_kernel(const int* __restrict__ icnt, float* __restrict__ dinv,
                                   int* __restrict__ cursor, int N) {
    int i = blockIdx.x * 256 + threadIdx.x;
    if (i < N) { dinv[i] = rsqrtf((float)(icnt[i] + 1)); cursor[i] = 0; }
}

// ---- 3-phase multi-block exclusive scan of icnt -> offs (chunk = 1024 elems) ----

__global__ __launch_bounds__(256) void blocksum_kernel(const int* __restrict__ icnt,
                                                       int* __restrict__ bsum, int N) {
    int b = blockIdx.x, t = threadIdx.x;
    int base = b * 1024 + t * 4;
    int s = 0;
    if (base + 3 < N) {
        int4 v = *(const int4*)&icnt[base];
        s = v.x + v.y + v.z + v.w;
    } else {
        for (int i = 0; i < 4; i++) if (base + i < N) s += icnt[base + i];
    }
    __shared__ int red[256];
    red[t] = s;
    __syncthreads();
    for (int o = 128; o > 0; o >>= 1) {
        if (t < o) red[t] += red[t + o];
        __syncthreads();
    }
    if (t == 0) bsum[b] = red[0];
}

__global__ __launch_bounds__(128) void bscan_kernel(int* __restrict__ bsum,
                                                    int* __restrict__ offs, int NB, int N) {
    __shared__ int sh[128];
    int t = threadIdx.x;
    int v = (t < NB) ? bsum[t] : 0;
    sh[t] = v;
    __syncthreads();
    for (int o = 1; o < 128; o <<= 1) {
        int u = (t >= o) ? sh[t - o] : 0;
        __syncthreads();
        sh[t] += u;
        __syncthreads();
    }
    if (t < NB) bsum[t] = sh[t] - v;   // exclusive block offsets
    if (t == 127) offs[N] = sh[127];   // grand total
}

__global__ __launch_bounds__(256) void offs_kernel(const int* __restrict__ icnt,
                                                   const int* __restrict__ bsum,
                                                   int* __restrict__ offs, int N) {
    int b = blockIdx.x, t = threadIdx.x;
    int base = b * 1024 + t * 4;
    int v[4]; int s = 0;
#pragma unroll
    for (int i = 0; i < 4; i++) {
        int idx = base + i;
        v[i] = (idx < N) ? icnt[idx] : 0;
        s += v[i];
    }
    __shared__ int sh[256];
    sh[t] = s;
    __syncthreads();
    for (int o = 1; o < 256; o <<= 1) {
        int u = (t >= o) ? sh[t - o] : 0;
        __syncthreads();
        sh[t] += u;
        __syncthreads();
    }
    int off = bsum[b] + sh[t] - s;
#pragma unroll
    for (int i = 0; i < 4; i++) {
        int idx = base + i;
        if (idx < N) { offs[idx] = off; off += v[i]; }
    }
}

// ---------------- weight prep ----------------

__global__ void w1_tile_kernel(const float* __restrict__ src,
                               __hip_bfloat16* __restrict__ dst) {
    int t = blockIdx.x * 256 + threadIdx.x;
    if (t < 512 * 256) {
        int k = t >> 8, n = t & 255;
        int kc = k >> 5, kl = k & 31;
        int slot = kl >> 3, pos = kl & 7;
        int sl = slot ^ ((n >> 1) & 3);
        dst[kc * 8192 + n * 32 + sl * 8 + pos] = __float2bfloat16(src[t]);
    }
}

__global__ void transpose_cvt_kernel(const float* __restrict__ src,
                                     __hip_bfloat16* __restrict__ dst, int K, int N) {
    int t = blockIdx.x * 256 + threadIdx.x;
    if (t < K * N) { int k = t / N, n = t % N; dst[n * K + k] = __float2bfloat16(src[t]); }
}

// ---------------- fused MLP + scatter fat kernel ----------------
// mlp (MFMA/LDS-bound, 134 us) and scatter (random-atomic latency-bound,
// 167 us, no LDS, 4 VGPR) are INDEPENDENT and use complementary pipes; a
// same-stream launch serializes them. Fat kernel: blocks [0,MB) run the mlp
// body, blocks [MB,MB+SB) run the scatter body -> they co-schedule on the CUs.
// Branch is block-uniform; mlp's barriers stay inside its path. The 32 KB
// static LDS + ~100 VGPR now apply to scatter blocks too (occupancy 24->16
// waves/CU worst case) -- bounded downside vs the 301 us serial sum.

__global__ __launch_bounds__(256) void mlp_scatter_kernel(
    const float* __restrict__ x, const __hip_bfloat16* __restrict__ W1Tt,
    const float* __restrict__ b1, const __hip_bfloat16* __restrict__ W2T,
    const float* __restrict__ b2, __hip_bfloat16* __restrict__ h, int M, int MB,
    const int* __restrict__ row, const int* __restrict__ col,
    const int* __restrict__ offs, int* __restrict__ cursor,
    int* __restrict__ csr, int E)
{
    __shared__ __align__(16) short lds[16384];  // 2 x 16 KB W1 double buffer
    short* Ts = lds;                            // phase-B strip buffer aliases buf0

    if (blockIdx.x >= MB) {
        // ---- scatter body (round-2 proven, unchanged) ----
        int e = (blockIdx.x - MB) * 256 + threadIdx.x;
        if (e < E) {
            int c = col[e];
            int p = offs[c] + atomicAdd(&cursor[c], 1);
            csr[p] = row[e];
        }
        return;
    }

    // ---- mlp body (round-6 proven, unchanged; row-major h) ----
    const int t = threadIdx.x;
    const int lane = t & 63, wave = t >> 6;
    const int lm = lane & 15, quad = lane >> 4;
    const int block_m = blockIdx.x * 64;
    const short* w2s = (const short*)W2T;
    const char*  w1b = (const char*)W1Tt;

    const int grow = block_m + wave * 16 + lm;
    const bool rok = grow < M;
    const float* xrow = x + (size_t)grow * 512 + quad * 8;
    const floatx4 z4 = (floatx4){0.f, 0.f, 0.f, 0.f};

    const int chunk_base = wave * 4;
    const int gl_off = lane * 16;

    auto stageB = [&](int kc, int buf) {
#pragma unroll
        for (int it = 0; it < 4; it++) {
            int chunk = chunk_base + it;
            gll16(w1b + (size_t)kc * 16384 + chunk * 1024 + gl_off,
                  &lds[buf * 8192 + chunk * 512]);
        }
    };

    floatx4 accA[16];
#pragma unroll
    for (int i = 0; i < 16; i++) accA[i] = z4;

    stageB(0, 0);
    floatx4 a0  = rok ? *(const floatx4*)xrow       : z4;
    floatx4 a1  = rok ? *(const floatx4*)(xrow + 4) : z4;
    floatx4 na0 = z4, na1 = z4;

    const int boff = lm * 32 + ((quad ^ ((lm >> 1) & 3)) << 3);

    __syncthreads();

    for (int kc = 0; kc < 16; kc++) {
        if (kc < 15) {
            stageB(kc + 1, (kc + 1) & 1);
            const float* p = xrow + (kc + 1) * 32;
            na0 = rok ? *(const floatx4*)p       : z4;
            na1 = rok ? *(const floatx4*)(p + 4) : z4;
        }
        short8 afs;
#pragma unroll
        for (int j = 0; j < 4; j++) { afs[j] = f2bf(a0[j]); afs[4 + j] = f2bf(a1[j]); }
        bf16x8 af = __builtin_bit_cast(bf16x8, afs);
        const short* bb = &lds[(kc & 1) * 8192];
#pragma unroll
        for (int nt = 0; nt < 16; nt++) {
            bf16x8 bfr = __builtin_bit_cast(bf16x8, *(const short8*)&bb[nt * 512 + boff]);
            accA[nt] = __builtin_amdgcn_mfma_f32_16x16x32_bf16(af, bfr, accA[nt], 0, 0, 0);
        }
        a0 = na0; a1 = na1;
        __syncthreads();
    }

    floatx4 accB[4];
#pragma unroll
    for (int j = 0; j < 4; j++) accB[j] = z4;

#pragma unroll
    for (int s = 0; s < 4; s++) {
        __syncthreads();
#pragma unroll
        for (int ntl = 0; ntl < 4; ntl++) {
            int nt = s * 4 + ntl;
            float bv = b1[nt * 16 + lm];
#pragma unroll
            for (int r = 0; r < 4; r++) {
                int rowl = wave * 16 + quad * 4 + r;
                Ts[rowl * 72 + ntl * 16 + lm] = f2bf(fmaxf(accA[nt][r] + bv, 0.f));
            }
        }
        __syncthreads();
#pragma unroll
        for (int kk = 0; kk < 2; kk++) {
            bf16x8 af2 = __builtin_bit_cast(bf16x8,
                *(const short8*)&Ts[(wave * 16 + lm) * 72 + kk * 32 + quad * 8]);
#pragma unroll
            for (int nt = 0; nt < 4; nt++) {
                bf16x8 bfr = __builtin_bit_cast(bf16x8,
                    *(const short8*)&w2s[(size_t)(nt * 16 + lm) * 256 + s * 64 + kk * 32 + quad * 8]);
                accB[nt] = __builtin_amdgcn_mfma_f32_16x16x32_bf16(af2, bfr, accB[nt], 0, 0, 0);
            }
        }
    }

#pragma unroll
    for (int nt = 0; nt < 4; nt++) {
        int colg = nt * 16 + lm;
        float bv = b2[colg];
#pragma unroll
        for (int r = 0; r < 4; r++) {
            int rowg = block_m + wave * 16 + quad * 4 + r;
            if (rowg < M)
                h[(size_t)rowg * 64 + colg] = __float2bfloat16(accB[nt][r] + bv);
        }
    }
}

// ---------------- propagation: wave/node; 8 groups x 8-feature chunks ----------
// Round-6 proven version: rounds fully unrolled with BATCHED loads (4 always,
// 4 more under wave-uniform cnt>32 guard) -> 4-8 gathers in flight per wave.

__global__ __launch_bounds__(256) void prop_kernel(
    const __hip_bfloat16* __restrict__ z_in, const __hip_bfloat16* __restrict__ h,
    const float* __restrict__ dinv, const int* __restrict__ offs,
    const int* __restrict__ csr, __hip_bfloat16* __restrict__ z_out,
    float* __restrict__ out, int N, int last)
{
    int node = blockIdx.x * 4 + (threadIdx.x >> 6);
    if (node >= N) return;  // wave-uniform
    int lane = threadIdx.x & 63;
    int g = lane >> 3, i = lane & 7;
    const short* zs = (const short*)z_in;
    const short* hs = (const short*)h;
    float di = dinv[node];
    int s = offs[node], e = offs[node + 1];
    float acc[8] = {0.f, 0.f, 0.f, 0.f, 0.f, 0.f, 0.f, 0.f};

    for (int j0 = s; j0 < e; j0 += 64) {
        int jj = j0 + lane;
        int nbr = 0; float dn = 0.f;
        if (jj < e) { nbr = csr[jj]; dn = dinv[nbr]; }
        int cnt = min(64, e - j0);
        bool more = cnt > 32;  // wave-uniform

        int nb[8]; float wv[8];
#pragma unroll
        for (int tt = 0; tt < 8; tt++) {
            int src = tt * 8 + g;
            nb[tt] = __shfl(nbr, src);
            wv[tt] = __shfl(dn, src);   // 0 for padded slots
        }

        short8 zv[8];
#pragma unroll
        for (int tt = 0; tt < 4; tt++)
            zv[tt] = *(const short8*)&zs[(size_t)nb[tt] * 64 + i * 8];
        if (more) {
#pragma unroll
            for (int tt = 4; tt < 8; tt++)
                zv[tt] = *(const short8*)&zs[(size_t)nb[tt] * 64 + i * 8];
        }
#pragma unroll
        for (int tt = 0; tt < 4; tt++)
#pragma unroll
            for (int j = 0; j < 8; j++)
                acc[j] = fmaf(wv[tt], bf2f(zv[tt][j]), acc[j]);
        if (more) {
#pragma unroll
            for (int tt = 4; tt < 8; tt++)
#pragma unroll
                for (int j = 0; j < 8; j++)
                    acc[j] = fmaf(wv[tt], bf2f(zv[tt][j]), acc[j]);
        }
    }
    // combine the 8 neighbor groups
#pragma unroll
    for (int j = 0; j < 8; j++) {
        acc[j] += __shfl_xor(acc[j], 8);
        acc[j] += __shfl_xor(acc[j], 16);
        acc[j] += __shfl_xor(acc[j], 32);
    }

    short8 zv = *(const short8*)&zs[(size_t)node * 64 + i * 8];
    short8 hv = *(const short8*)&hs[(size_t)node * 64 + i * 8];
    float v[8];
#pragma unroll
    for (int j = 0; j < 8; j++)
        v[j] = 0.9f * (di * acc[j] + di * di * bf2f(zv[j])) + 0.1f * bf2f(hv[j]);

    if (!last) {
        if (g == 0) {
            short8 o8;
#pragma unroll
            for (int j = 0; j < 8; j++) o8[j] = f2bf(v[j]);
            *(short8*)&((short*)z_out)[(size_t)node * 64 + i * 8] = o8;
        }
    } else {
        float m = v[0];
#pragma unroll
        for (int j = 1; j < 8; j++) m = fmaxf(m, v[j]);
        m = fmaxf(m, __shfl_xor(m, 1));
        m = fmaxf(m, __shfl_xor(m, 2));
        m = fmaxf(m, __shfl_xor(m, 4));
        float ss = 0.f;
#pragma unroll
        for (int j = 0; j < 8; j++) ss += expf(v[j] - m);
        ss += __shfl_xor(ss, 1);
        ss += __shfl_xor(ss, 2);
        ss += __shfl_xor(ss, 4);
        float ls = m + logf(ss);
        if (g == 0) {
            floatx4 o0, o1;
#pragma unroll
            for (int j = 0; j < 4; j++) { o0[j] = v[j] - ls; o1[j] = v[4 + j] - ls; }
            *(floatx4*)&out[(size_t)node * 64 + i * 8]     = o0;
            *(floatx4*)&out[(size_t)node * 64 + i * 8 + 4] = o1;
        }
    }
}

// ---------------- launch ----------------

extern "C" void kernel_launch(void* const* d_in, const int* in_sizes, int n_in,
                              void* d_out, int out_size, void* d_ws, size_t ws_size,
                              hipStream_t stream) {
    const float* x  = (const float*)d_in[0];
    const int*   ei = (const int*)d_in[1];
    const float* W1 = (const float*)d_in[2];
    const float* b1 = (const float*)d_in[3];
    const float* W2 = (const float*)d_in[4];
    const float* b2 = (const float*)d_in[5];
    float* out = (float*)d_out;

    const int FIN = 512, FH = 256, FO = 64;
    const int N = in_sizes[0] / FIN;
    const int E = in_sizes[1] / 2;
    const int* erow = ei;
    const int* ecol = ei + E;

    char* w = (char*)d_ws;
    size_t o = 0;
    auto take = [&](size_t bytes) -> void* {
        void* p = w + o;
        o += (bytes + 511) & ~(size_t)511;
        return p;
    };
    int*   icnt   = (int*)  take((size_t)N * 4);
    float* dinv   = (float*)take((size_t)N * 4);
    int*   offs   = (int*)  take((size_t)(N + 1) * 4);
    int*   cursor = (int*)  take((size_t)N * 4);
    int*   csr    = (int*)  take((size_t)E * 4);
    int*   bsum   = (int*)  take((size_t)128 * 4);
    __hip_bfloat16* W1Tt = (__hip_bfloat16*)take((size_t)FIN * FH * 2);
    __hip_bfloat16* W2T  = (__hip_bfloat16*)take((size_t)FH * FO * 2);
    __hip_bfloat16* hbuf = (__hip_bfloat16*)take((size_t)N * FO * 2);
    __hip_bfloat16* zA   = (__hip_bfloat16*)take((size_t)N * FO * 2);
    __hip_bfloat16* zB   = (__hip_bfloat16*)out;  // alias: bf16 z (12.8 MB) in f32 out
                                                  // (25.6 MB); k=9 reads zA, overwrites out

    const int NB = (N + 1023) / 1024;  // scan blocks (<=128 for bscan)

    (void)hipMemsetAsync(icnt, 0, (size_t)N * 4, stream);
    count_kernel<<<(E + 255) / 256, 256, 0, stream>>>(ecol, icnt, E);
    dinv_cursor_kernel<<<(N + 255) / 256, 256, 0, stream>>>(icnt, dinv, cursor, N);
    blocksum_kernel<<<NB, 256, 0, stream>>>(icnt, bsum, N);
    bscan_kernel<<<1, 128, 0, stream>>>(bsum, offs, NB, N);
    offs_kernel<<<NB, 256, 0, stream>>>(icnt, bsum, offs, N);
    w1_tile_kernel<<<(FIN * FH + 255) / 256, 256, 0, stream>>>(W1, W1Tt);
    transpose_cvt_kernel<<<(FH * FO + 255) / 256, 256, 0, stream>>>(W2, W2T, FH, FO);

    const int MB = (N + 63) / 64;      // mlp blocks
    const int SB = (E + 255) / 256;    // scatter blocks
    mlp_scatter_kernel<<<MB + SB, 256, 0, stream>>>(x, W1Tt, b1, W2T, b2, hbuf, N, MB,
                                                    erow, ecol, offs, cursor, csr, E);

    const __hip_bfloat16* zin = hbuf;
    for (int k = 0; k < 10; k++) {
        int last = (k == 9);
        __hip_bfloat16* zout = (k & 1) ? zB : zA;
        prop_kernel<<<(N + 3) / 4, 256, 0, stream>>>(zin, hbuf, dinv, offs, csr,
                                                     zout, out, N, last);
        zin = zout;
    }
}